// Round 3
// baseline (649.510 us; speedup 1.0000x reference)
//
#include <hip/hip_runtime.h>

#define BATCH 16
#define C_IN 128
#define C_OUT 128
#define HH 128
#define WW 128
#define HDIM 512
#define OH 126
#define OW 126
#define NTAP 9
#define WPB (NTAP * C_OUT * C_IN)          /* 147456 w-elements per batch */
#define XT_ELEMS ((size_t)BATCH * HH * WW * C_IN)

typedef __attribute__((ext_vector_type(8))) short short8;
typedef __attribute__((ext_vector_type(4))) float floatx4;
typedef __attribute__((ext_vector_type(16))) float floatx16;

__device__ __forceinline__ unsigned short f2bf(float f) {
    union { float f; unsigned u; } v; v.f = f;
    unsigned r = v.u + 0x7FFF + ((v.u >> 16) & 1);   // RNE
    return (unsigned short)(r >> 16);
}

// ---------------- Fused prep kernel ----------------
// blocks [0, 768)        : gen_w  — hypernet weight GEMM -> wbuf (bf16)
// blocks [768, 768+8192) : xpose  — x (b,ci,y,x) f32 -> xT (b, y*128+x, ci) bf16
// blocks [8960, 8968)    : gen_b  — per-sample bias (fp32 exact)
// Stages are fully independent; fusing overlaps gen_w's 302MB Wh stream with
// xpose's 192MB stream. gen_w blocks first.
//
// wbuf layout: npr = tap*16384 + (ci>>4)*2048 + co*16 + (ci&15)
// i.e. [b][tap][cig 8][co 128][cil 16] — conv's per-tap A-fragment load of a
// 16-ci chunk is a single fully-contiguous 2KB wave read.
#define GENW_BLOCKS 768
#define XPOSE_BLOCKS 8192
#define PREP_BLOCKS (GENW_BLOCKS + XPOSE_BLOCKS + 8)

__global__ __launch_bounds__(256) void prep_kernel(
    const float* __restrict__ x, unsigned short* __restrict__ xT,
    const float* __restrict__ h, const float* __restrict__ Wh,
    const float* __restrict__ bh, unsigned short* __restrict__ wbuf,
    const float* __restrict__ Wb, const float* __restrict__ bb,
    float* __restrict__ bbuf)
{
    __shared__ __align__(16) char smem[16640];   // 16*520*2 == 64*65*4 == 16640
    const int bid = blockIdx.x;
    const int tid = threadIdx.x;

    if (bid < GENW_BLOCKS) {
        // ---- gen_w: C[16][147456] = h(16x512) @ Wh^T via 16x16x32 bf16 MFMA
        unsigned short* hl = (unsigned short*)smem;      // 16 x 520 padded
        for (int i = tid; i < 16 * 512; i += 256) {
            int m = i >> 9, k = i & 511;
            hl[m * 520 + k] = f2bf(h[i]);
        }
        __syncthreads();
        const int wave = tid >> 6, lane = tid & 63;
        const int m  = lane & 15;     // batch row
        const int kg = lane >> 4;     // k-group 0..3

        short8 afr[16];               // all A fragments for K=512, loaded once
        #pragma unroll
        for (int kk = 0; kk < 16; ++kk)
            afr[kk] = *(const short8*)&hl[m * 520 + kk * 32 + kg * 8];

        const int wtile0 = (bid * 4 + wave) * 3;
        for (int t = 0; t < 3; ++t) {
            const int n0  = (wtile0 + t) * 16;
            const int npr = n0 + (lane & 15);            // this lane's n' (col)
            // decode layout: npr = tap*16384 + cig*2048 + co*16 + cil
            const int tap = npr >> 14;
            const int cig = (npr >> 11) & 7;
            const int co  = (npr >> 4) & 127;
            const int ci  = cig * 16 + (npr & 15);
            const size_t whrow = (size_t)co * (C_IN * NTAP) + (size_t)ci * NTAP + tap;
            const float* wr = Wh + whrow * HDIM + kg * 8;

            floatx4 acc = {0.f, 0.f, 0.f, 0.f};
            #pragma unroll
            for (int kk = 0; kk < 16; ++kk) {
                float4 b0 = *(const float4*)(wr + kk * 32);
                float4 b1 = *(const float4*)(wr + kk * 32 + 4);
                short8 bfr;
                bfr[0] = (short)f2bf(b0.x); bfr[1] = (short)f2bf(b0.y);
                bfr[2] = (short)f2bf(b0.z); bfr[3] = (short)f2bf(b0.w);
                bfr[4] = (short)f2bf(b1.x); bfr[5] = (short)f2bf(b1.y);
                bfr[6] = (short)f2bf(b1.z); bfr[7] = (short)f2bf(b1.w);
                acc = __builtin_amdgcn_mfma_f32_16x16x32_bf16(afr[kk], bfr, acc, 0, 0, 0);
            }
            const float bias = bh[whrow];
            #pragma unroll
            for (int r = 0; r < 4; ++r) {
                int bt = kg * 4 + r;                     // batch = (lane>>4)*4 + reg
                wbuf[(size_t)bt * WPB + npr] = f2bf(acc[r] + bias);
            }
        }
    } else if (bid < GENW_BLOCKS + XPOSE_BLOCKS) {
        // ---- xpose: x (b,ci,y,x) fp32 -> xT (b, y*128+x, ci) bf16
        const int xb = bid - GENW_BLOCKS;
        float (*tile)[65] = (float (*)[65])smem;
        const int b   = xb >> 9;
        const int ci0 = ((xb >> 8) & 1) * 64;
        const int p0  = (xb & 255) * 64;
        const int lp  = tid & 63;
        const int lg  = tid >> 6;
        const float* xbp = x + ((size_t)b * C_IN + ci0) * (HH * WW) + p0;
        #pragma unroll
        for (int i = 0; i < 16; ++i) {
            int ci = lg * 16 + i;
            tile[ci][lp] = xbp[(size_t)ci * (HH * WW) + lp];
        }
        __syncthreads();
        // Vectorized store: each thread packs a ci-pair -> 4B store; a full
        // wave writes 256B contiguous. LDS reads: 2-way bank alias (free).
        unsigned short* ob = xT + ((size_t)b * (HH * WW) + p0) * C_IN + ci0;
        #pragma unroll
        for (int j = 0; j < 8; ++j) {
            const int idx = j * 256 + tid;       // 0..2047
            const int p   = idx >> 5;            // 0..63
            const int cp  = (idx & 31) * 2;      // ci pair 0,2,..,62
            union { unsigned short s[2]; unsigned u; } pk;
            pk.s[0] = f2bf(tile[cp][p]);
            pk.s[1] = f2bf(tile[cp + 1][p]);
            *(unsigned*)&ob[(size_t)p * C_IN + cp] = pk.u;
        }
    } else {
        // ---- gen_b: per-sample bias (fp32 exact)
        const int idx = (bid - (GENW_BLOCKS + XPOSE_BLOCKS)) * 256 + tid; // 0..2047
        const int co = idx >> 4;
        const int b  = idx & 15;
        const float* hb = h + b * HDIM;
        const float* wr = Wb + co * HDIM;
        float acc = 0.f;
        for (int k = 0; k < HDIM; k += 4)
            acc += hb[k] * wr[k] + hb[k+1] * wr[k+1] + hb[k+2] * wr[k+2] + hb[k+3] * wr[k+3];
        bbuf[b * C_OUT + co] = acc + bb[co];
    }
}

// ---------------- conv as implicit GEMM, 32x32x16 bf16 MFMA.
// OCCUPANCY RESTRUCTURE (round 3): block = batch b, ONE out row y0, all 128
// cols, all 128 co. 4 waves = (co-half, col-half); per wave 2 M-tiles x 2
// N-tiles of 32x32 -> acc = 64 AGPRs (was 128). Total ~150 unified regs ->
// __launch_bounds__(256,3) = 3 blocks/CU = 3 waves/SIMD (was 2). Round-0
// counters (MfmaUtil 15.6%, VALUBusy 6.4%, occ 21.6%) showed conv is
// latency-bound with too few waves; +50% TLP is the direct fix. Costs: xT
// staging 3 rows per 1 out row (was 4 per 2) and wbuf L2 traffic 2x — both
// bandwidth we have (L2 ~135 B/cyc/CU, using <70), buying latency hiding.
// A-operand (wbuf) from global (L2-resident via XCD swizzle), B (patch) LDS.
__global__ __launch_bounds__(256, 3) void conv_kernel(
    const unsigned short* __restrict__ xT, const unsigned short* __restrict__ wbuf,
    const float* __restrict__ bbuf, float* __restrict__ out)
{
    __shared__ __align__(16) unsigned short patch[2][768 * 8]; // 2 x 12KB, swizzled
    __shared__ float biasl[C_OUT];
    const int tid = threadIdx.x, lane = tid & 63, wave = tid >> 6;

    // XCD-aware bijective swizzle: 2016 blocks = 8 XCDs * 252. XCD k owns
    // logical blocks [252k,252k+252) = exactly 2 whole batches -> per-XCD L2
    // working set = 2*288KB wbuf + streamed xT rows (adjacent-row reuse).
    const int lid = ((int)blockIdx.x & 7) * 252 + ((int)blockIdx.x >> 3);
    const int b  = lid / 126;
    const int y0 = lid % 126;
    if (tid < C_OUT) biasl[tid] = bbuf[b * C_OUT + tid];

    const int wco = wave >> 1;      // wave's co half (0/1)
    const int ch  = wave & 1;       // wave's column half (0/1)
    const int l31 = lane & 31, lh = lane >> 5;

    floatx16 acc[2][2];
    #pragma unroll
    for (int mt = 0; mt < 2; ++mt)
        #pragma unroll
        for (int cg = 0; cg < 2; ++cg)
            acc[mt][cg] = (floatx16)(0.f);

    const unsigned short* xTb = xT + (size_t)b * (HH * WW) * C_IN;
    const unsigned short* wb  = wbuf + (size_t)b * WPB;

    // stage ci-chunk cc (rows y0..y0+2, 128 cols, 16 ci) into patch[buf]
    auto stage = [&](int cc, int buf) {
        const int ci0 = cc * 16;
        #pragma unroll
        for (int i = 0; i < 3; ++i) {
            const int s0 = wave * 192 + i * 64;      // wave-uniform slot base
            const int s  = s0 + lane;                // slot 0..767
            const int r  = s >> 8;                   // 0..2
            const int c  = (s >> 1) & 127;
            const int hh = (s & 1) ^ ((c >> 2) & 1); // ci-half, swizzled
            const unsigned short* g =
                xTb + ((size_t)(y0 + r) * WW + c) * C_IN + ci0 + hh * 8;
            __builtin_amdgcn_global_load_lds(
                (const __attribute__((address_space(1))) void*)g,
                (__attribute__((address_space(3))) void*)(&patch[buf][s0 * 8]),
                16, 0, 0);
        }
    };

    stage(0, 0);
    __syncthreads();                          // prologue: chunk 0 resident

    for (int cc = 0; cc < 8; ++cc) {
        const int cur = cc & 1;
        if (cc < 7) stage(cc + 1, cur ^ 1);   // prefetch next chunk
        #pragma unroll
        for (int tap = 0; tap < 9; ++tap) {
            const int ky = tap / 3, kx = tap % 3;
            short8 af[2];
            // wbuf [tap][cig=cc][co][cil 16]: contiguous 1KB per wave half
            const unsigned short* wt =
                wb + (size_t)tap * (C_OUT * C_IN) + cc * 2048 + lh * 8;
            #pragma unroll
            for (int mt = 0; mt < 2; ++mt)
                af[mt] = *(const short8*)(wt + (wco * 64 + mt * 32 + l31) * 16);
            short8 bf[2];
            #pragma unroll
            for (int cg = 0; cg < 2; ++cg) {
                int c = ch * 64 + cg * 32 + l31 + kx;
                c = min(c, 127);              // clamped cols -> oxc>=126, unstored
                const int slot = ky * 256 + c * 2 + (lh ^ ((c >> 2) & 1));
                bf[cg] = *(const short8*)(&patch[cur][slot * 8]);
            }
            #pragma unroll
            for (int mt = 0; mt < 2; ++mt)
                #pragma unroll
                for (int cg = 0; cg < 2; ++cg)
                    acc[mt][cg] = __builtin_amdgcn_mfma_f32_32x32x16_bf16(
                        af[mt], bf[cg], acc[mt][cg], 0, 0, 0);
        }
        __syncthreads();   // orders reads of patch[cur] before overwrite;
                           // prefetch was issued before compute -> drain cheap
    }

    // Epilogue: C/D 32x32 layout: col=lane&31, row=(reg&3)+8*(reg>>2)+4*(lane>>5)
    const int oy = y0;
    const int ox = ch * 64 + l31;     // cg adds 32
    #pragma unroll
    for (int mt = 0; mt < 2; ++mt) {
        #pragma unroll
        for (int cg = 0; cg < 2; ++cg) {
            const int oxc = ox + cg * 32;
            if (oxc < OW) {
                #pragma unroll
                for (int rg = 0; rg < 16; ++rg) {
                    const int row = (rg & 3) + 8 * (rg >> 2) + 4 * lh;
                    const int co  = wco * 64 + mt * 32 + row;
                    out[(((size_t)b * C_OUT + co) * OH + oy) * OW + oxc] =
                        acc[mt][cg][rg] + biasl[co];
                }
            }
        }
    }
}

extern "C" void kernel_launch(void* const* d_in, const int* in_sizes, int n_in,
                              void* d_out, int out_size, void* d_ws, size_t ws_size,
                              hipStream_t stream) {
    const float* x  = (const float*)d_in[0];
    const float* h  = (const float*)d_in[1];
    const float* Wh = (const float*)d_in[2];
    const float* bh = (const float*)d_in[3];
    const float* Wb = (const float*)d_in[4];
    const float* bb = (const float*)d_in[5];
    float* out = (float*)d_out;

    unsigned short* xT   = (unsigned short*)d_ws;                   // 67108864 B
    unsigned short* wbuf = xT + XT_ELEMS;                           // 4718592 B
    float*          bbuf = (float*)(wbuf + (size_t)BATCH * WPB);    // 8192 B

    prep_kernel<<<PREP_BLOCKS, 256, 0, stream>>>(x, xT, h, Wh, bh, wbuf, Wb, bb, bbuf);
    conv_kernel<<<2016, 256, 0, stream>>>(xT, wbuf, bbuf, out);
}

// Round 4
// 628.937 us; speedup vs baseline: 1.0327x; 1.0327x over previous
//
#include <hip/hip_runtime.h>

#define BATCH 16
#define C_IN 128
#define C_OUT 128
#define HH 128
#define WW 128
#define HDIM 512
#define OH 126
#define OW 126
#define NTAP 9
#define WPB (NTAP * C_OUT * C_IN)          /* 147456 w-elements per batch */
#define XT_ELEMS ((size_t)BATCH * HH * WW * C_IN)

typedef __attribute__((ext_vector_type(8))) short short8;
typedef __attribute__((ext_vector_type(4))) float floatx4;
typedef __attribute__((ext_vector_type(16))) float floatx16;

__device__ __forceinline__ unsigned short f2bf(float f) {
    union { float f; unsigned u; } v; v.f = f;
    unsigned r = v.u + 0x7FFF + ((v.u >> 16) & 1);   // RNE
    return (unsigned short)(r >> 16);
}

// ---------------- Fused prep kernel ----------------
// blocks [0, 768)        : gen_w  — hypernet weight GEMM -> wbuf (bf16)
// blocks [768, 768+8192) : xpose  — x (b,ci,y,x) f32 -> xT (b, y*128+x, ci) bf16
// blocks [8960, 8968)    : gen_b  — per-sample bias (fp32 exact)
// Stages are fully independent; fusing overlaps gen_w's 302MB Wh stream with
// xpose's 192MB stream. gen_w blocks first.
//
// wbuf layout: npr = tap*16384 + (ci>>4)*2048 + co*16 + (ci&15)
// i.e. [b][tap][cig 8][co 128][cil 16] — conv's per-tap A-fragment load of a
// 16-ci chunk is a single fully-contiguous 2KB wave read.
#define GENW_BLOCKS 768
#define XPOSE_BLOCKS 8192
#define PREP_BLOCKS (GENW_BLOCKS + XPOSE_BLOCKS + 8)

__global__ __launch_bounds__(256) void prep_kernel(
    const float* __restrict__ x, unsigned short* __restrict__ xT,
    const float* __restrict__ h, const float* __restrict__ Wh,
    const float* __restrict__ bh, unsigned short* __restrict__ wbuf,
    const float* __restrict__ Wb, const float* __restrict__ bb,
    float* __restrict__ bbuf)
{
    __shared__ __align__(16) char smem[16640];   // 16*520*2 == 64*65*4 == 16640
    const int bid = blockIdx.x;
    const int tid = threadIdx.x;

    if (bid < GENW_BLOCKS) {
        // ---- gen_w: C[16][147456] = h(16x512) @ Wh^T via 16x16x32 bf16 MFMA
        unsigned short* hl = (unsigned short*)smem;      // 16 x 520 padded
        for (int i = tid; i < 16 * 512; i += 256) {
            int m = i >> 9, k = i & 511;
            hl[m * 520 + k] = f2bf(h[i]);
        }
        __syncthreads();
        const int wave = tid >> 6, lane = tid & 63;
        const int m  = lane & 15;     // batch row
        const int kg = lane >> 4;     // k-group 0..3

        short8 afr[16];               // all A fragments for K=512, loaded once
        #pragma unroll
        for (int kk = 0; kk < 16; ++kk)
            afr[kk] = *(const short8*)&hl[m * 520 + kk * 32 + kg * 8];

        const int wtile0 = (bid * 4 + wave) * 3;
        for (int t = 0; t < 3; ++t) {
            const int n0  = (wtile0 + t) * 16;
            const int npr = n0 + (lane & 15);            // this lane's n' (col)
            // decode layout: npr = tap*16384 + cig*2048 + co*16 + cil
            const int tap = npr >> 14;
            const int cig = (npr >> 11) & 7;
            const int co  = (npr >> 4) & 127;
            const int ci  = cig * 16 + (npr & 15);
            const size_t whrow = (size_t)co * (C_IN * NTAP) + (size_t)ci * NTAP + tap;
            const float* wr = Wh + whrow * HDIM + kg * 8;

            floatx4 acc = {0.f, 0.f, 0.f, 0.f};
            #pragma unroll
            for (int kk = 0; kk < 16; ++kk) {
                float4 b0 = *(const float4*)(wr + kk * 32);
                float4 b1 = *(const float4*)(wr + kk * 32 + 4);
                short8 bfr;
                bfr[0] = (short)f2bf(b0.x); bfr[1] = (short)f2bf(b0.y);
                bfr[2] = (short)f2bf(b0.z); bfr[3] = (short)f2bf(b0.w);
                bfr[4] = (short)f2bf(b1.x); bfr[5] = (short)f2bf(b1.y);
                bfr[6] = (short)f2bf(b1.z); bfr[7] = (short)f2bf(b1.w);
                acc = __builtin_amdgcn_mfma_f32_16x16x32_bf16(afr[kk], bfr, acc, 0, 0, 0);
            }
            const float bias = bh[whrow];
            #pragma unroll
            for (int r = 0; r < 4; ++r) {
                int bt = kg * 4 + r;                     // batch = (lane>>4)*4 + reg
                wbuf[(size_t)bt * WPB + npr] = f2bf(acc[r] + bias);
            }
        }
    } else if (bid < GENW_BLOCKS + XPOSE_BLOCKS) {
        // ---- xpose: x (b,ci,y,x) fp32 -> xT (b, y*128+x, ci) bf16
        const int xb = bid - GENW_BLOCKS;
        float (*tile)[65] = (float (*)[65])smem;
        const int b   = xb >> 9;
        const int ci0 = ((xb >> 8) & 1) * 64;
        const int p0  = (xb & 255) * 64;
        const int lp  = tid & 63;
        const int lg  = tid >> 6;
        const float* xbp = x + ((size_t)b * C_IN + ci0) * (HH * WW) + p0;
        #pragma unroll
        for (int i = 0; i < 16; ++i) {
            int ci = lg * 16 + i;
            tile[ci][lp] = xbp[(size_t)ci * (HH * WW) + lp];
        }
        __syncthreads();
        // Vectorized store: each thread packs a ci-pair -> 4B store; a full
        // wave writes 256B contiguous. LDS reads: 2-way bank alias (free).
        unsigned short* ob = xT + ((size_t)b * (HH * WW) + p0) * C_IN + ci0;
        #pragma unroll
        for (int j = 0; j < 8; ++j) {
            const int idx = j * 256 + tid;       // 0..2047
            const int p   = idx >> 5;            // 0..63
            const int cp  = (idx & 31) * 2;      // ci pair 0,2,..,62
            union { unsigned short s[2]; unsigned u; } pk;
            pk.s[0] = f2bf(tile[cp][p]);
            pk.s[1] = f2bf(tile[cp + 1][p]);
            *(unsigned*)&ob[(size_t)p * C_IN + cp] = pk.u;
        }
    } else {
        // ---- gen_b: per-sample bias (fp32 exact)
        const int idx = (bid - (GENW_BLOCKS + XPOSE_BLOCKS)) * 256 + tid; // 0..2047
        const int co = idx >> 4;
        const int b  = idx & 15;
        const float* hb = h + b * HDIM;
        const float* wr = Wb + co * HDIM;
        float acc = 0.f;
        for (int k = 0; k < HDIM; k += 4)
            acc += hb[k] * wr[k] + hb[k+1] * wr[k+1] + hb[k+2] * wr[k+2] + hb[k+3] * wr[k+3];
        bbuf[b * C_OUT + co] = acc + bb[co];
    }
}

// ---------------- conv as implicit GEMM, 32x32x16 bf16 MFMA.
// Block = batch b, ONE out row y0, all 128 cols, all 128 co. 4 waves =
// (co-half, col-half); per wave 2 M-tiles x 2 N-tiles of 32x32 (64 AGPR acc).
//
// vmcnt-ORDERING FIX (round 4): global_load_lds (stage) and the af global
// loads share ONE vmcnt counter with IN-ORDER retirement. If af loads are
// issued after stage(cc+1), the s_waitcnt before the first MFMA transitively
// waits for the ~900cy HBM stage loads — serializing every chunk's compute
// behind the prefetch (why rounds 2-3 were null). Fix: issue ALL 18 af
// fragments for the chunk into registers BEFORE stage(cc+1); af (L2-hit)
// then retires while stage is still outstanding, and the 36-MFMA tap loop
// covers most of the stage latency before the end-of-chunk barrier drain.
__global__ __launch_bounds__(256, 2) void conv_kernel(
    const unsigned short* __restrict__ xT, const unsigned short* __restrict__ wbuf,
    const float* __restrict__ bbuf, float* __restrict__ out)
{
    __shared__ __align__(16) unsigned short patch[2][768 * 8]; // 2 x 12KB, swizzled
    __shared__ float biasl[C_OUT];
    const int tid = threadIdx.x, lane = tid & 63, wave = tid >> 6;

    // XCD-aware bijective swizzle: 2016 blocks = 8 XCDs * 252 = 2 batches/XCD.
    const int lid = ((int)blockIdx.x & 7) * 252 + ((int)blockIdx.x >> 3);
    const int b  = lid / 126;
    const int y0 = lid % 126;
    if (tid < C_OUT) biasl[tid] = bbuf[b * C_OUT + tid];

    const int wco = wave >> 1;      // wave's co half (0/1)
    const int ch  = wave & 1;       // wave's column half (0/1)
    const int l31 = lane & 31, lh = lane >> 5;

    floatx16 acc[2][2];
    #pragma unroll
    for (int mt = 0; mt < 2; ++mt)
        #pragma unroll
        for (int cg = 0; cg < 2; ++cg)
            acc[mt][cg] = (floatx16)(0.f);

    const unsigned short* xTb = xT + (size_t)b * (HH * WW) * C_IN;
    const unsigned short* wb  = wbuf + (size_t)b * WPB;

    // stage ci-chunk cc (rows y0..y0+2, 128 cols, 16 ci) into patch[buf]
    auto stage = [&](int cc, int buf) {
        const int ci0 = cc * 16;
        #pragma unroll
        for (int i = 0; i < 3; ++i) {
            const int s0 = wave * 192 + i * 64;      // wave-uniform slot base
            const int s  = s0 + lane;                // slot 0..767
            const int r  = s >> 8;                   // 0..2
            const int c  = (s >> 1) & 127;
            const int hh = (s & 1) ^ ((c >> 2) & 1); // ci-half, swizzled
            const unsigned short* g =
                xTb + ((size_t)(y0 + r) * WW + c) * C_IN + ci0 + hh * 8;
            __builtin_amdgcn_global_load_lds(
                (const __attribute__((address_space(1))) void*)g,
                (__attribute__((address_space(3))) void*)(&patch[buf][s0 * 8]),
                16, 0, 0);
        }
    };

    stage(0, 0);
    __syncthreads();                          // prologue: chunk 0 resident

    for (int cc = 0; cc < 8; ++cc) {
        const int cur = cc & 1;

        // (1) ALL af loads for this chunk, issued BEFORE the stage loads so
        // they are OLDER in the vmcnt stream (in-order retirement => they
        // complete without waiting on the HBM staging). Statically indexed
        // (full unroll) so af[][] stays in registers (72 VGPRs).
        short8 af[9][2];
        {
            const unsigned short* wtc = wb + cc * 2048 + lh * 8;
            #pragma unroll
            for (int tap = 0; tap < 9; ++tap)
                #pragma unroll
                for (int mt = 0; mt < 2; ++mt)
                    af[tap][mt] = *(const short8*)
                        (wtc + (size_t)tap * (C_OUT * C_IN)
                             + (wco * 64 + mt * 32 + l31) * 16);
        }
        __builtin_amdgcn_sched_barrier(0);    // pin: af older than stage
        if (cc < 7) stage(cc + 1, cur ^ 1);   // prefetch next chunk (HBM)
        __builtin_amdgcn_sched_barrier(0);    // pin: stage issued before taps

        #pragma unroll
        for (int tap = 0; tap < 9; ++tap) {
            const int ky = tap / 3, kx = tap % 3;
            short8 bf[2];
            #pragma unroll
            for (int cg = 0; cg < 2; ++cg) {
                int c = ch * 64 + cg * 32 + l31 + kx;
                c = min(c, 127);              // clamped cols -> oxc>=126, unstored
                const int slot = ky * 256 + c * 2 + (lh ^ ((c >> 2) & 1));
                bf[cg] = *(const short8*)(&patch[cur][slot * 8]);
            }
            #pragma unroll
            for (int mt = 0; mt < 2; ++mt)
                #pragma unroll
                for (int cg = 0; cg < 2; ++cg)
                    acc[mt][cg] = __builtin_amdgcn_mfma_f32_32x32x16_bf16(
                        af[tap][mt], bf[cg], acc[mt][cg], 0, 0, 0);
        }
        __syncthreads();   // orders reads of patch[cur] before overwrite; the
                           // vmcnt(0) drain here finds stage mostly complete
                           // (compute phase ran with it in flight)
    }

    // Epilogue: C/D 32x32 layout: col=lane&31, row=(reg&3)+8*(reg>>2)+4*(lane>>5)
    const int oy = y0;
    const int ox = ch * 64 + l31;     // cg adds 32
    #pragma unroll
    for (int mt = 0; mt < 2; ++mt) {
        #pragma unroll
        for (int cg = 0; cg < 2; ++cg) {
            const int oxc = ox + cg * 32;
            if (oxc < OW) {
                #pragma unroll
                for (int rg = 0; rg < 16; ++rg) {
                    const int row = (rg & 3) + 8 * (rg >> 2) + 4 * lh;
                    const int co  = wco * 64 + mt * 32 + row;
                    out[(((size_t)b * C_OUT + co) * OH + oy) * OW + oxc] =
                        acc[mt][cg][rg] + biasl[co];
                }
            }
        }
    }
}

extern "C" void kernel_launch(void* const* d_in, const int* in_sizes, int n_in,
                              void* d_out, int out_size, void* d_ws, size_t ws_size,
                              hipStream_t stream) {
    const float* x  = (const float*)d_in[0];
    const float* h  = (const float*)d_in[1];
    const float* Wh = (const float*)d_in[2];
    const float* bh = (const float*)d_in[3];
    const float* Wb = (const float*)d_in[4];
    const float* bb = (const float*)d_in[5];
    float* out = (float*)d_out;

    unsigned short* xT   = (unsigned short*)d_ws;                   // 67108864 B
    unsigned short* wbuf = xT + XT_ELEMS;                           // 4718592 B
    float*          bbuf = (float*)(wbuf + (size_t)BATCH * WPB);    // 8192 B

    prep_kernel<<<PREP_BLOCKS, 256, 0, stream>>>(x, xT, h, Wh, bh, wbuf, Wb, bb, bbuf);
    conv_kernel<<<2016, 256, 0, stream>>>(xT, wbuf, bbuf, out);
}